// Round 15
// baseline (103.895 us; speedup 1.0000x reference)
//
#include <hip/hip_runtime.h>
#include <cstddef>

#define ALPHA 0.2f
constexpr int B = 2, N = 8192, F = 256, D = 128;
constexpr int M = B * N;
constexpr int NB = 2048;          // value buckets per batch
constexpr int SUB = 128;          // elements per sub-block for stable scatter
constexpr int P = N / SUB;        // 64 sub-blocks per batch
constexpr int GB = 2;             // buckets per k_bsum block
constexpr int NBB = NB / GB;      // 1024 bsum blocks per batch
constexpr int QROWS = 8;          // rows per k_query block
constexpr int BPT = NB / 128;     // buckets per thread in k_scat local scan (16)
constexpr int CH = 16;            // buckets per scan chunk
constexpr int NCH = NB / CH;      // 128 chunks per batch

// ---- fixed monotone bucket map over [-4.5,4.5) (clamped ends stay exactly correct) ----
#define BMIN (-4.5f)
#define BSCALE ((float)NB / 9.0f)
__device__ inline int bucket_of(float x) {
  int g = (int)((x - BMIN) * BSCALE);
  return g < 0 ? 0 : (g > NB - 1 ? NB - 1 : g);
}

// ---------------- GEMM (fp32, per-thread 4x4, 2x b128/k -> FMA-bound) + fused f1/f2 ----------------
__global__ __launch_bounds__(512) void k_gemm(const float* __restrict__ seq,
                                              const float* __restrict__ Wf,
                                              const float* __restrict__ w1,
                                              const float* __restrict__ b1,
                                              const float* __restrict__ w2,
                                              const float* __restrict__ b2,
                                              float* __restrict__ fts,
                                              float* __restrict__ f1,
                                              float* __restrict__ f2) {
  __shared__ float As[32][68];    // [k][row], padded
  __shared__ float Bs[32][128];
  const int m0 = blockIdx.x * 64;
  const int t = threadIdx.x;
  const int colg = t & 31;        // cols colg*4 .. +3
  const int rowg = t >> 5;        // rows rowg*4 .. +3 (16 groups)
  float acc[4][4];
#pragma unroll
  for (int r = 0; r < 4; ++r)
#pragma unroll
    for (int c = 0; c < 4; ++c) acc[r][c] = 0.f;

  for (int kc = 0; kc < F; kc += 32) {
    {  // stage A 64x32 transposed [k][row]: one float4 per thread
      const int row = t >> 3, k4 = t & 7;
      const float4 v = *reinterpret_cast<const float4*>(
          &seq[(size_t)(m0 + row) * F + kc + k4 * 4]);
      As[k4 * 4 + 0][row] = v.x; As[k4 * 4 + 1][row] = v.y;
      As[k4 * 4 + 2][row] = v.z; As[k4 * 4 + 3][row] = v.w;
    }
#pragma unroll
    for (int it = 0; it < 2; ++it) {  // stage B 32x128
      const int f = t + it * 512;
      const int row = f >> 5, c4 = f & 31;
      *reinterpret_cast<float4*>(&Bs[row][c4 * 4]) =
          *reinterpret_cast<const float4*>(&Wf[(size_t)(kc + row) * D + c4 * 4]);
    }
    __syncthreads();
#pragma unroll
    for (int k = 0; k < 32; ++k) {
      const float4 a4 = *reinterpret_cast<const float4*>(&As[k][rowg * 4]);
      const float4 b4 = *reinterpret_cast<const float4*>(&Bs[k][colg * 4]);
      acc[0][0] += a4.x * b4.x; acc[0][1] += a4.x * b4.y; acc[0][2] += a4.x * b4.z; acc[0][3] += a4.x * b4.w;
      acc[1][0] += a4.y * b4.x; acc[1][1] += a4.y * b4.y; acc[1][2] += a4.y * b4.z; acc[1][3] += a4.y * b4.w;
      acc[2][0] += a4.z * b4.x; acc[2][1] += a4.z * b4.y; acc[2][2] += a4.z * b4.z; acc[2][3] += a4.z * b4.w;
      acc[3][0] += a4.w * b4.x; acc[3][1] += a4.w * b4.y; acc[3][2] += a4.w * b4.z; acc[3][3] += a4.w * b4.w;
    }
    __syncthreads();
  }
#pragma unroll
  for (int r = 0; r < 4; ++r) {
    float4 v = {acc[r][0], acc[r][1], acc[r][2], acc[r][3]};
    *reinterpret_cast<float4*>(&fts[(size_t)(m0 + rowg * 4 + r) * D + colg * 4]) = v;
  }
  // fused f1/f2: thread's 4 cols partial dot, width-32 shuffle reduce covers the full row
  const float w1v[4] = {w1[colg * 4], w1[colg * 4 + 1], w1[colg * 4 + 2], w1[colg * 4 + 3]};
  const float w2v[4] = {w2[colg * 4], w2[colg * 4 + 1], w2[colg * 4 + 2], w2[colg * 4 + 3]};
  const float b1v = b1[0], b2v = b2[0];
#pragma unroll
  for (int r = 0; r < 4; ++r) {
    float s1 = acc[r][0] * w1v[0] + acc[r][1] * w1v[1] + acc[r][2] * w1v[2] + acc[r][3] * w1v[3];
    float s2 = acc[r][0] * w2v[0] + acc[r][1] * w2v[1] + acc[r][2] * w2v[2] + acc[r][3] * w2v[3];
#pragma unroll
    for (int off = 16; off > 0; off >>= 1) {
      s1 += __shfl_down(s1, off, 32);
      s2 += __shfl_down(s2, off, 32);
    }
    if (colg == 0) {
      const int row = m0 + rowg * 4 + r;
      f1[row] = s1 + b1v;
      f2[row] = s2 + b2v;
    }
  }
}

// ---------------- per-sub-block histogram (deterministic, ushort out) ----------------
__global__ __launch_bounds__(128) void k_hist(const float* __restrict__ f2,
                                              int* __restrict__ bid,
                                              unsigned short* __restrict__ histcnt) {
  __shared__ int hist[NB];
  const int b = blockIdx.x / P, p = blockIdx.x % P;
  const int t = threadIdx.x;
  for (int i = t; i < NB; i += 128) hist[i] = 0;
  const int j = p * SUB + t;
  float x = f2[b * N + j];
  int g = bucket_of(x);
  bid[b * N + j] = g;
  __syncthreads();
  atomicAdd(&hist[g], 1);
  __syncthreads();
  for (int i = t; i < NB; i += 128)
    histcnt[((size_t)(b * P + p)) * NB + i] = (unsigned short)hist[i];
}

// ---------------- per-bucket prefix over sub-blocks + bucket totals ----------------
__global__ __launch_bounds__(256) void k_sub(const unsigned short* __restrict__ histcnt,
                                             unsigned short* __restrict__ substart,
                                             int* __restrict__ btot) {
  const int gid = blockIdx.x * 256 + threadIdx.x;  // 0 .. B*NB-1
  const int b = gid / NB, g = gid % NB;
  int run = 0;
  for (int pp = 0; pp < P; ++pp) {
    substart[((size_t)(b * P + pp)) * NB + g] = (unsigned short)run;
    run += histcnt[((size_t)(b * P + pp)) * NB + g];
  }
  btot[b * NB + g] = run;
}

// ---------------- scatter of keys/weights (packed kw), local bucket scan ----------------
__global__ __launch_bounds__(128) void k_scat(const float* __restrict__ f2,
                                              const int* __restrict__ bid,
                                              const unsigned short* __restrict__ substart,
                                              const int* __restrict__ btot,
                                              int* __restrict__ bstart,
                                              float4* __restrict__ kw,
                                              int* __restrict__ idxs) {
  __shared__ int bstart_lds[NB];
  __shared__ int bids[SUB];
  __shared__ int wsum2[2];
  const int b = blockIdx.x / P, p = blockIdx.x % P;
  const int t = threadIdx.x;
  const int lane = t & 63, wave = t >> 6;
  const size_t bN = (size_t)b * N;

  int c[BPT];
  int loc = 0;
#pragma unroll
  for (int i = 0; i < BPT; ++i) { c[i] = btot[b * NB + t * BPT + i]; loc += c[i]; }
  int incl = loc;
#pragma unroll
  for (int off = 1; off < 64; off <<= 1) {
    int y = __shfl_up(incl, off);
    if (lane >= off) incl += y;
  }
  if (lane == 63) wsum2[wave] = incl;
  __syncthreads();
  if (wave == 1) incl += wsum2[0];
  int excl = incl - loc;
#pragma unroll
  for (int i = 0; i < BPT; ++i) { bstart_lds[t * BPT + i] = excl; excl += c[i]; }
  __syncthreads();
  if (p == 0) {
    for (int i = t; i < NB; i += 128) bstart[b * (NB + 1) + i] = bstart_lds[i];
    if (t == 0) bstart[b * (NB + 1) + NB] = N;
  }

  const int j = p * SUB + t;
  const int g = bid[bN + j];
  bids[t] = g;
  __syncthreads();
  int off = bstart_lds[g] + (int)substart[((size_t)(b * P + p)) * NB + g];
  for (int jj = 0; jj < t; ++jj) off += (bids[jj] == g);
  const float x = f2[bN + j];
  kw[bN + off] = make_float4(x, expf(x), expf(ALPHA * x), 0.f);
  idxs[bN + off] = j;
}

// ---------------- permute fts into scattered order (full-grid gather) ----------------
__global__ __launch_bounds__(256) void k_perm(const float* __restrict__ fts,
                                              const int* __restrict__ idxs,
                                              float* __restrict__ fts_s) {
  const int tid = blockIdx.x * 256 + threadIdx.x;    // one float4 each
  const int eg = tid >> 5;                           // global scattered row (b*N+e)
  const int q = tid & 31;
  const int b = eg / N;
  const int j = idxs[eg];
  *reinterpret_cast<float4*>(&fts_s[(size_t)eg * D + q * 4]) =
      *reinterpret_cast<const float4*>(&fts[((size_t)b * N + j) * D + q * 4]);
}

// ---------------- per-bucket weighted sums (streaming, high TLP) ----------------
__global__ __launch_bounds__(128) void k_bsum(const float* __restrict__ fts_s,
                                              const float4* __restrict__ kw,
                                              const int* __restrict__ bstart,
                                              float* __restrict__ Wp, float* __restrict__ Wn,
                                              float* __restrict__ Cp, float* __restrict__ Cn) {
  const int b = blockIdx.x / NBB, blk = blockIdx.x % NBB;
  const int d = threadIdx.x;
  const int gbase = blk * GB;
  const size_t bN = (size_t)b * N;
  for (int gg = 0; gg < GB; ++gg) {
    const int g = gbase + gg;
    const int e0 = bstart[b * (NB + 1) + g], e1 = bstart[b * (NB + 1) + g + 1];
    float ap = 0.f, an = 0.f, sp = 0.f, sn = 0.f;
    int e = e0;
    for (; e + 4 <= e1; e += 4) {
      const float* vp = &fts_s[(bN + e) * D + d];
      const float v0 = vp[0], v1 = vp[D], v2 = vp[2 * D], v3 = vp[3 * D];
      const float4 k0 = kw[bN + e], k1 = kw[bN + e + 1], k2 = kw[bN + e + 2], k3 = kw[bN + e + 3];
      ap += k0.y * v0 + k1.y * v1 + k2.y * v2 + k3.y * v3;
      an += k0.z * v0 + k1.z * v1 + k2.z * v2 + k3.z * v3;
      sp += k0.y + k1.y + k2.y + k3.y;
      sn += k0.z + k1.z + k2.z + k3.z;
    }
    for (; e < e1; ++e) {
      const float v = fts_s[(bN + e) * D + d];
      const float4 k0 = kw[bN + e];
      ap += k0.y * v; an += k0.z * v; sp += k0.y; sn += k0.z;
    }
    Wp[((size_t)b * NB + g) * D + d] = ap;
    Wn[((size_t)b * NB + g) * D + d] = an;
    if (d == 0) { Cp[b * NB + g] = sp; Cn[b * NB + g] = sn; }
  }
}

// ---------------- chunk sums (CH=16 buckets per chunk; wide: 256 blocks) ----------------
__global__ __launch_bounds__(128) void k_chsum(const float* __restrict__ Wp, const float* __restrict__ Wn,
                                               const float* __restrict__ Cp, const float* __restrict__ Cn,
                                               float* __restrict__ CSp, float* __restrict__ CSn,
                                               float* __restrict__ CCp, float* __restrict__ CCn) {
  const int b = blockIdx.x / NCH, ch = blockIdx.x % NCH;
  const int d = threadIdx.x;
  const size_t base = (size_t)b * NB;
  float sp = 0.f, sn = 0.f;
  for (int gg = 0; gg < CH; ++gg) {
    const int g = ch * CH + gg;
    sp += Wp[(base + g) * D + d];
    sn += Wn[(base + g) * D + d];
  }
  CSp[((size_t)b * NCH + ch) * D + d] = sp;
  CSn[((size_t)b * NCH + ch) * D + d] = sn;
  if (d == 0) {
    float cp = 0.f, cn = 0.f;
    for (int gg = 0; gg < CH; ++gg) { const int g = ch * CH + gg; cp += Cp[base + g]; cn += Cn[base + g]; }
    CCp[b * NCH + ch] = cp; CCn[b * NCH + ch] = cn;
  }
}

// ---------------- final bucket-boundary values (wide: 256 blocks, redundant chunk-offset sum) ----------------
__global__ __launch_bounds__(128) void k_chfinal(const float* __restrict__ Wp, const float* __restrict__ Wn,
                                                 const float* __restrict__ Cp, const float* __restrict__ Cn,
                                                 const float* __restrict__ CSp, const float* __restrict__ CSn,
                                                 const float* __restrict__ CCp, const float* __restrict__ CCn,
                                                 float* __restrict__ BPos, float* __restrict__ BNeg,
                                                 float* __restrict__ CpB, float* __restrict__ CnB) {
  const int b = blockIdx.x / NCH, ch = blockIdx.x % NCH;
  const int d = threadIdx.x;
  const size_t base = (size_t)b * NB;
  const size_t cbase = (size_t)b * NCH;
  // chunk-level offsets: prefix of CSn (ascending), suffix of CSp (descending)
  float offn = 0.f, offp = 0.f;
  for (int c2 = 0; c2 < ch; ++c2)        offn += CSn[(cbase + c2) * D + d];
  for (int c2 = ch + 1; c2 < NCH; ++c2)  offp += CSp[(cbase + c2) * D + d];
  // within-chunk running sums
  float runn = offn;
  for (int gg = 0; gg < CH; ++gg) {
    const int g = ch * CH + gg;
    BNeg[(base + g) * D + d] = runn;
    runn += Wn[(base + g) * D + d];
  }
  float runp = offp;
  for (int gg = CH - 1; gg >= 0; --gg) {
    const int g = ch * CH + gg;
    BPos[(base + g) * D + d] = runp;
    runp += Wp[(base + g) * D + d];
  }
  if (d == 0) {
    float on = 0.f, op = 0.f;
    for (int c2 = 0; c2 < ch; ++c2)       on += CCn[cbase + c2];
    for (int c2 = ch + 1; c2 < NCH; ++c2) op += CCp[cbase + c2];
    float rn = on;
    for (int gg = 0; gg < CH; ++gg) { const int g = ch * CH + gg; CnB[base + g] = rn; rn += Cn[base + g]; }
    float rp = op;
    for (int gg = CH - 1; gg >= 0; --gg) { const int g = ch * CH + gg; CpB[base + g] = rp; rp += Cp[base + g]; }
  }
}

// ---------------- query: 32 lanes x float4 per row, branchless boundary loop ----------------
__global__ __launch_bounds__(256) void k_query(const float* __restrict__ f1,
                                               const float4* __restrict__ kw,
                                               const float* __restrict__ fts_s,
                                               const int* __restrict__ bstart,
                                               const float* __restrict__ BPos, const float* __restrict__ BNeg,
                                               const float* __restrict__ CpB, const float* __restrict__ CnB,
                                               const float* __restrict__ bias,
                                               float* __restrict__ out) {
  const int r = threadIdx.x >> 5;
  const int lane = threadIdx.x & 31;
  const int row = blockIdx.x * QROWS + r;
  const int b = row / N;
  const size_t bN = (size_t)b * N;
  const int d4 = lane * 4;
  const float f1v = f1[row];
  const float th = -f1v;
  const int g = bucket_of(th);
  const int base = bstart[b * (NB + 1) + g];
  const int end  = bstart[b * (NB + 1) + g + 1];
  float4 sn = *reinterpret_cast<const float4*>(&BNeg[((size_t)b * NB + g) * D + d4]);
  float4 sp = *reinterpret_cast<const float4*>(&BPos[((size_t)b * NB + g) * D + d4]);
  float cn = CnB[b * NB + g];
  float cp = CpB[b * NB + g];
  for (int e = base; e < end; ++e) {
    const float4 kwe = kw[bN + e];
    const float4 v = *reinterpret_cast<const float4*>(&fts_s[(bN + e) * D + d4]);
    const bool neg = (kwe.x <= th);
    const float wn = neg ? kwe.z : 0.f;
    const float wp = neg ? 0.f : kwe.y;
    sn.x += wn * v.x; sn.y += wn * v.y; sn.z += wn * v.z; sn.w += wn * v.w;
    sp.x += wp * v.x; sp.y += wp * v.y; sp.z += wp * v.z; sp.w += wp * v.w;
    cn += wn; cp += wp;
  }
  const float wqp = expf(f1v), wqn = expf(ALPHA * f1v);
  const float denom = wqp * cp + wqn * cn;
  const float inv = 1.0f / denom;
  const float4 bi = *reinterpret_cast<const float4*>(&bias[d4]);
  float4 val;
  val.x = (wqp * sp.x + wqn * sn.x) * inv + bi.x;
  val.y = (wqp * sp.y + wqn * sn.y) * inv + bi.y;
  val.z = (wqp * sp.z + wqn * sn.z) * inv + bi.z;
  val.w = (wqp * sp.w + wqn * sn.w) * inv + bi.w;
  val.x = val.x >= 0.f ? val.x : ALPHA * val.x;
  val.y = val.y >= 0.f ? val.y : ALPHA * val.y;
  val.z = val.z >= 0.f ? val.z : ALPHA * val.z;
  val.w = val.w >= 0.f ? val.w : ALPHA * val.w;
  *reinterpret_cast<float4*>(&out[(size_t)row * D + d4]) = val;
}

extern "C" void kernel_launch(void* const* d_in, const int* in_sizes, int n_in,
                              void* d_out, int out_size, void* d_ws, size_t ws_size,
                              hipStream_t stream) {
  const float* seq  = (const float*)d_in[0];
  const float* Wf   = (const float*)d_in[1];
  const float* w1   = (const float*)d_in[2];
  const float* b1   = (const float*)d_in[3];
  const float* w2   = (const float*)d_in[4];
  const float* b2   = (const float*)d_in[5];
  const float* bias = (const float*)d_in[6];
  float* out = (float*)d_out;

  char* ws = (char*)d_ws;
  size_t off = 0;
  auto alloc = [&](size_t bytes) -> void* {
    void* p = ws + off;
    off = (off + bytes + 255) & ~(size_t)255;
    return p;
  };

  float*  fts     = (float*) alloc((size_t)M * D * 4);
  float*  fts_s   = (float*) alloc((size_t)M * D * 4);
  float*  f1      = (float*) alloc((size_t)M * 4);
  float*  f2      = (float*) alloc((size_t)M * 4);
  float4* kw      = (float4*)alloc((size_t)M * 16);
  int*    idxs    = (int*)   alloc((size_t)M * 4);
  int*    bid     = (int*)   alloc((size_t)M * 4);
  unsigned short* histcnt  = (unsigned short*)alloc((size_t)B * P * NB * 2);
  unsigned short* substart = (unsigned short*)alloc((size_t)B * P * NB * 2);
  int*    btot    = (int*)   alloc((size_t)B * NB * 4);
  int*    bstart  = (int*)   alloc((size_t)B * (NB + 1) * 4);
  float*  Wp      = (float*) alloc((size_t)B * NB * D * 4);
  float*  Wn      = (float*) alloc((size_t)B * NB * D * 4);
  float*  Cp      = (float*) alloc((size_t)B * NB * 4);
  float*  Cn      = (float*) alloc((size_t)B * NB * 4);
  float*  CSp     = (float*) alloc((size_t)B * NCH * D * 4);
  float*  CSn     = (float*) alloc((size_t)B * NCH * D * 4);
  float*  CCp     = (float*) alloc((size_t)B * NCH * 4);
  float*  CCn     = (float*) alloc((size_t)B * NCH * 4);
  float*  BPos    = (float*) alloc((size_t)B * NB * D * 4);
  float*  BNeg    = (float*) alloc((size_t)B * NB * D * 4);
  float*  CpB     = (float*) alloc((size_t)B * NB * 4);
  float*  CnB     = (float*) alloc((size_t)B * NB * 4);

  hipLaunchKernelGGL(k_gemm,    dim3(M / 64),          dim3(512), 0, stream, seq, Wf, w1, b1, w2, b2, fts, f1, f2);
  hipLaunchKernelGGL(k_hist,    dim3(B * P),           dim3(128), 0, stream, f2, bid, histcnt);
  hipLaunchKernelGGL(k_sub,     dim3(B * NB / 256),    dim3(256), 0, stream, histcnt, substart, btot);
  hipLaunchKernelGGL(k_scat,    dim3(B * P),           dim3(128), 0, stream, f2, bid, substart, btot, bstart,
                     kw, idxs);
  hipLaunchKernelGGL(k_perm,    dim3(M * D / 4 / 256), dim3(256), 0, stream, fts, idxs, fts_s);
  hipLaunchKernelGGL(k_bsum,    dim3(B * NBB),         dim3(128), 0, stream, fts_s, kw, bstart, Wp, Wn, Cp, Cn);
  hipLaunchKernelGGL(k_chsum,   dim3(B * NCH),         dim3(128), 0, stream, Wp, Wn, Cp, Cn, CSp, CSn, CCp, CCn);
  hipLaunchKernelGGL(k_chfinal, dim3(B * NCH),         dim3(128), 0, stream, Wp, Wn, Cp, Cn, CSp, CSn, CCp, CCn,
                     BPos, BNeg, CpB, CnB);
  hipLaunchKernelGGL(k_query,   dim3(M / QROWS),       dim3(256), 0, stream, f1, kw, fts_s, bstart,
                     BPos, BNeg, CpB, CnB, bias, out);
}

// Round 16
// 86.138 us; speedup vs baseline: 1.2061x; 1.2061x over previous
//
#include <hip/hip_runtime.h>
#include <cstddef>

#define ALPHA 0.2f
constexpr int B = 2, N = 8192, F = 256, D = 128;
constexpr int M = B * N;
constexpr int NB = 2048;          // value buckets per batch
constexpr int SUB = 128;          // elements per sub-block for stable scatter
constexpr int P = N / SUB;        // 64 sub-blocks per batch
constexpr int GB = 2;             // buckets per k_bsum block
constexpr int NBB = NB / GB;      // 1024 bsum blocks per batch
constexpr int GSZ = 64;           // buckets per scan group
constexpr int NGRP = NB / GSZ;    // 32 groups per batch
constexpr int QROWS = 8;          // rows per k_query block
constexpr int DSL = 4;            // d's per k_scan slice
constexpr int NSL = D / DSL;      // 32 slices
constexpr int BPT = NB / 128;     // buckets per thread in k_scat local scan (16)

// ---- fixed monotone bucket map over [-4.5,4.5) (clamped ends stay exactly correct) ----
#define BMIN (-4.5f)
#define BSCALE ((float)NB / 9.0f)
__device__ inline int bucket_of(float x) {
  int g = (int)((x - BMIN) * BSCALE);
  return g < 0 ? 0 : (g > NB - 1 ? NB - 1 : g);
}

// ---------------- GEMM (fp32, per-thread 4x4, 2x b128/k -> FMA-bound) + fused f1/f2 ----------------
__global__ __launch_bounds__(512) void k_gemm(const float* __restrict__ seq,
                                              const float* __restrict__ Wf,
                                              const float* __restrict__ w1,
                                              const float* __restrict__ b1,
                                              const float* __restrict__ w2,
                                              const float* __restrict__ b2,
                                              float* __restrict__ fts,
                                              float* __restrict__ f1,
                                              float* __restrict__ f2) {
  __shared__ float As[32][68];    // [k][row], padded
  __shared__ float Bs[32][128];
  const int m0 = blockIdx.x * 64;
  const int t = threadIdx.x;
  const int colg = t & 31;        // cols colg*4 .. +3
  const int rowg = t >> 5;        // rows rowg*4 .. +3 (16 groups)
  float acc[4][4];
#pragma unroll
  for (int r = 0; r < 4; ++r)
#pragma unroll
    for (int c = 0; c < 4; ++c) acc[r][c] = 0.f;

  for (int kc = 0; kc < F; kc += 32) {
    {  // stage A 64x32 transposed [k][row]: one float4 per thread
      const int row = t >> 3, k4 = t & 7;
      const float4 v = *reinterpret_cast<const float4*>(
          &seq[(size_t)(m0 + row) * F + kc + k4 * 4]);
      As[k4 * 4 + 0][row] = v.x; As[k4 * 4 + 1][row] = v.y;
      As[k4 * 4 + 2][row] = v.z; As[k4 * 4 + 3][row] = v.w;
    }
#pragma unroll
    for (int it = 0; it < 2; ++it) {  // stage B 32x128
      const int f = t + it * 512;
      const int row = f >> 5, c4 = f & 31;
      *reinterpret_cast<float4*>(&Bs[row][c4 * 4]) =
          *reinterpret_cast<const float4*>(&Wf[(size_t)(kc + row) * D + c4 * 4]);
    }
    __syncthreads();
#pragma unroll
    for (int k = 0; k < 32; ++k) {
      const float4 a4 = *reinterpret_cast<const float4*>(&As[k][rowg * 4]);
      const float4 b4 = *reinterpret_cast<const float4*>(&Bs[k][colg * 4]);
      acc[0][0] += a4.x * b4.x; acc[0][1] += a4.x * b4.y; acc[0][2] += a4.x * b4.z; acc[0][3] += a4.x * b4.w;
      acc[1][0] += a4.y * b4.x; acc[1][1] += a4.y * b4.y; acc[1][2] += a4.y * b4.z; acc[1][3] += a4.y * b4.w;
      acc[2][0] += a4.z * b4.x; acc[2][1] += a4.z * b4.y; acc[2][2] += a4.z * b4.z; acc[2][3] += a4.z * b4.w;
      acc[3][0] += a4.w * b4.x; acc[3][1] += a4.w * b4.y; acc[3][2] += a4.w * b4.z; acc[3][3] += a4.w * b4.w;
    }
    __syncthreads();
  }
#pragma unroll
  for (int r = 0; r < 4; ++r) {
    float4 v = {acc[r][0], acc[r][1], acc[r][2], acc[r][3]};
    *reinterpret_cast<float4*>(&fts[(size_t)(m0 + rowg * 4 + r) * D + colg * 4]) = v;
  }
  // fused f1/f2: thread's 4 cols partial dot, width-32 shuffle reduce covers the full row
  const float w1v[4] = {w1[colg * 4], w1[colg * 4 + 1], w1[colg * 4 + 2], w1[colg * 4 + 3]};
  const float w2v[4] = {w2[colg * 4], w2[colg * 4 + 1], w2[colg * 4 + 2], w2[colg * 4 + 3]};
  const float b1v = b1[0], b2v = b2[0];
#pragma unroll
  for (int r = 0; r < 4; ++r) {
    float s1 = acc[r][0] * w1v[0] + acc[r][1] * w1v[1] + acc[r][2] * w1v[2] + acc[r][3] * w1v[3];
    float s2 = acc[r][0] * w2v[0] + acc[r][1] * w2v[1] + acc[r][2] * w2v[2] + acc[r][3] * w2v[3];
#pragma unroll
    for (int off = 16; off > 0; off >>= 1) {
      s1 += __shfl_down(s1, off, 32);
      s2 += __shfl_down(s2, off, 32);
    }
    if (colg == 0) {
      const int row = m0 + rowg * 4 + r;
      f1[row] = s1 + b1v;
      f2[row] = s2 + b2v;
    }
  }
}

// ---------------- per-sub-block histogram (deterministic) ----------------
__global__ __launch_bounds__(128) void k_hist(const float* __restrict__ f2,
                                              int* __restrict__ bid,
                                              int* __restrict__ histcnt) {
  __shared__ int hist[NB];
  const int b = blockIdx.x / P, p = blockIdx.x % P;
  const int t = threadIdx.x;
  for (int i = t; i < NB; i += 128) hist[i] = 0;
  const int j = p * SUB + t;
  float x = f2[b * N + j];
  int g = bucket_of(x);
  bid[b * N + j] = g;
  __syncthreads();
  atomicAdd(&hist[g], 1);
  __syncthreads();
  for (int i = t; i < NB; i += 128)
    histcnt[((size_t)(b * P + p)) * NB + i] = hist[i];
}

// ---------------- per-bucket prefix over sub-blocks + bucket totals ----------------
__global__ __launch_bounds__(256) void k_sub(const int* __restrict__ histcnt,
                                             int* __restrict__ substart,
                                             int* __restrict__ btot) {
  const int gid = blockIdx.x * 256 + threadIdx.x;  // 0 .. B*NB-1
  const int b = gid / NB, g = gid % NB;
  int run = 0;
  for (int pp = 0; pp < P; ++pp) {
    substart[((size_t)(b * P + pp)) * NB + g] = run;
    run += histcnt[((size_t)(b * P + pp)) * NB + g];
  }
  btot[b * NB + g] = run;
}

// ---------------- scatter of keys/weights (packed kw), local bucket scan ----------------
__global__ __launch_bounds__(128) void k_scat(const float* __restrict__ f2,
                                              const int* __restrict__ bid,
                                              const int* __restrict__ substart,
                                              const int* __restrict__ btot,
                                              int* __restrict__ bstart,
                                              float4* __restrict__ kw,
                                              int* __restrict__ idxs) {
  __shared__ int bstart_lds[NB];
  __shared__ int bids[SUB];
  __shared__ int wsum2[2];
  const int b = blockIdx.x / P, p = blockIdx.x % P;
  const int t = threadIdx.x;
  const int lane = t & 63, wave = t >> 6;
  const size_t bN = (size_t)b * N;

  int c[BPT];
  int loc = 0;
#pragma unroll
  for (int i = 0; i < BPT; ++i) { c[i] = btot[b * NB + t * BPT + i]; loc += c[i]; }
  int incl = loc;
#pragma unroll
  for (int off = 1; off < 64; off <<= 1) {
    int y = __shfl_up(incl, off);
    if (lane >= off) incl += y;
  }
  if (lane == 63) wsum2[wave] = incl;
  __syncthreads();
  if (wave == 1) incl += wsum2[0];
  int excl = incl - loc;
#pragma unroll
  for (int i = 0; i < BPT; ++i) { bstart_lds[t * BPT + i] = excl; excl += c[i]; }
  __syncthreads();
  if (p == 0) {
    for (int i = t; i < NB; i += 128) bstart[b * (NB + 1) + i] = bstart_lds[i];
    if (t == 0) bstart[b * (NB + 1) + NB] = N;
  }

  const int j = p * SUB + t;
  const int g = bid[bN + j];
  bids[t] = g;
  __syncthreads();
  int off = bstart_lds[g] + substart[((size_t)(b * P + p)) * NB + g];
  for (int jj = 0; jj < t; ++jj) off += (bids[jj] == g);
  const float x = f2[bN + j];
  kw[bN + off] = make_float4(x, expf(x), expf(ALPHA * x), 0.f);
  idxs[bN + off] = j;
}

// ---------------- permute fts into scattered order (full-grid gather) ----------------
__global__ __launch_bounds__(256) void k_perm(const float* __restrict__ fts,
                                              const int* __restrict__ idxs,
                                              float* __restrict__ fts_s) {
  const int tid = blockIdx.x * 256 + threadIdx.x;    // one float4 each
  const int eg = tid >> 5;                           // global scattered row (b*N+e)
  const int q = tid & 31;
  const int b = eg / N;
  const int j = idxs[eg];
  *reinterpret_cast<float4*>(&fts_s[(size_t)eg * D + q * 4]) =
      *reinterpret_cast<const float4*>(&fts[((size_t)b * N + j) * D + q * 4]);
}

// ---------------- per-bucket weighted sums (streaming, high TLP) ----------------
__global__ __launch_bounds__(128) void k_bsum(const float* __restrict__ fts_s,
                                              const float4* __restrict__ kw,
                                              const int* __restrict__ bstart,
                                              float* __restrict__ Wp, float* __restrict__ Wn,
                                              float* __restrict__ Cp, float* __restrict__ Cn) {
  const int b = blockIdx.x / NBB, blk = blockIdx.x % NBB;
  const int d = threadIdx.x;
  const int gbase = blk * GB;
  const size_t bN = (size_t)b * N;
  for (int gg = 0; gg < GB; ++gg) {
    const int g = gbase + gg;
    const int e0 = bstart[b * (NB + 1) + g], e1 = bstart[b * (NB + 1) + g + 1];
    float ap = 0.f, an = 0.f, sp = 0.f, sn = 0.f;
    int e = e0;
    for (; e + 4 <= e1; e += 4) {
      const float* vp = &fts_s[(bN + e) * D + d];
      const float v0 = vp[0], v1 = vp[D], v2 = vp[2 * D], v3 = vp[3 * D];
      const float4 k0 = kw[bN + e], k1 = kw[bN + e + 1], k2 = kw[bN + e + 2], k3 = kw[bN + e + 3];
      ap += k0.y * v0 + k1.y * v1 + k2.y * v2 + k3.y * v3;
      an += k0.z * v0 + k1.z * v1 + k2.z * v2 + k3.z * v3;
      sp += k0.y + k1.y + k2.y + k3.y;
      sn += k0.z + k1.z + k2.z + k3.z;
    }
    for (; e < e1; ++e) {
      const float v = fts_s[(bN + e) * D + d];
      const float4 k0 = kw[bN + e];
      ap += k0.y * v; an += k0.z * v; sp += k0.y; sn += k0.z;
    }
    Wp[((size_t)b * NB + g) * D + d] = ap;
    Wn[((size_t)b * NB + g) * D + d] = an;
    if (d == 0) { Cp[b * NB + g] = sp; Cn[b * NB + g] = sn; }
  }
}

// ---------------- fused 3-phase bucket-boundary scan ----------------
__global__ __launch_bounds__(128) void k_scan(const float* __restrict__ Wp, const float* __restrict__ Wn,
                                              const float* __restrict__ Cp, const float* __restrict__ Cn,
                                              float* __restrict__ BPos, float* __restrict__ BNeg,
                                              float* __restrict__ CpB, float* __restrict__ CnB) {
  __shared__ float gp[NGRP][DSL], gn[NGRP][DSL];
  __shared__ float cgp[NGRP], cgn[NGRP];
  const int b = blockIdx.x / NSL, sl = blockIdx.x % NSL;
  const int t = threadIdx.x;                 // 128 = NGRP(32) x DSL(4)
  const int d4 = t & (DSL - 1), grp = t >> 2;
  const int d = sl * DSL + d4;
  const size_t base = (size_t)b * NB;

  float sp = 0.f, sn = 0.f;
  for (int gg = 0; gg < GSZ; ++gg) {
    const int g = grp * GSZ + gg;
    sp += Wp[(base + g) * D + d];
    sn += Wn[(base + g) * D + d];
  }
  gp[grp][d4] = sp; gn[grp][d4] = sn;
  if (sl == 0 && d4 == 0) {
    float cp = 0.f, cn = 0.f;
    for (int gg = 0; gg < GSZ; ++gg) { const int g = grp * GSZ + gg; cp += Cp[base + g]; cn += Cn[base + g]; }
    cgp[grp] = cp; cgn[grp] = cn;
  }
  __syncthreads();

  if (t < DSL) {
    float run = 0.f;
    for (int g2 = 0; g2 < NGRP; ++g2) { const float v = gn[g2][t]; gn[g2][t] = run; run += v; }
  } else if (t < 2 * DSL) {
    const int dd = t - DSL;
    float run = 0.f;
    for (int g2 = NGRP - 1; g2 >= 0; --g2) { const float v = gp[g2][dd]; gp[g2][dd] = run; run += v; }
  } else if (sl == 0 && t == 2 * DSL) {
    float run = 0.f;
    for (int g2 = 0; g2 < NGRP; ++g2) { const float v = cgn[g2]; cgn[g2] = run; run += v; }
  } else if (sl == 0 && t == 2 * DSL + 1) {
    float run = 0.f;
    for (int g2 = NGRP - 1; g2 >= 0; --g2) { const float v = cgp[g2]; cgp[g2] = run; run += v; }
  }
  __syncthreads();

  float runn = gn[grp][d4];
  for (int gg = 0; gg < GSZ; ++gg) {
    const int g = grp * GSZ + gg;
    BNeg[(base + g) * D + d] = runn;
    runn += Wn[(base + g) * D + d];
  }
  float runp = gp[grp][d4];
  for (int gg = GSZ - 1; gg >= 0; --gg) {
    const int g = grp * GSZ + gg;
    BPos[(base + g) * D + d] = runp;
    runp += Wp[(base + g) * D + d];
  }
  if (sl == 0 && d4 == 0) {
    float rn = cgn[grp];
    for (int gg = 0; gg < GSZ; ++gg) { const int g = grp * GSZ + gg; CnB[base + g] = rn; rn += Cn[base + g]; }
    float rp = cgp[grp];
    for (int gg = GSZ - 1; gg >= 0; --gg) { const int g = grp * GSZ + gg; CpB[base + g] = rp; rp += Cp[base + g]; }
  }
}

// ---------------- query: 32 lanes x float4 per row, branchless boundary loop ----------------
__global__ __launch_bounds__(256) void k_query(const float* __restrict__ f1,
                                               const float4* __restrict__ kw,
                                               const float* __restrict__ fts_s,
                                               const int* __restrict__ bstart,
                                               const float* __restrict__ BPos, const float* __restrict__ BNeg,
                                               const float* __restrict__ CpB, const float* __restrict__ CnB,
                                               const float* __restrict__ bias,
                                               float* __restrict__ out) {
  const int r = threadIdx.x >> 5;
  const int lane = threadIdx.x & 31;
  const int row = blockIdx.x * QROWS + r;
  const int b = row / N;
  const size_t bN = (size_t)b * N;
  const int d4 = lane * 4;
  const float f1v = f1[row];
  const float th = -f1v;
  const int g = bucket_of(th);
  const int base = bstart[b * (NB + 1) + g];
  const int end  = bstart[b * (NB + 1) + g + 1];
  float4 sn = *reinterpret_cast<const float4*>(&BNeg[((size_t)b * NB + g) * D + d4]);
  float4 sp = *reinterpret_cast<const float4*>(&BPos[((size_t)b * NB + g) * D + d4]);
  float cn = CnB[b * NB + g];
  float cp = CpB[b * NB + g];
  for (int e = base; e < end; ++e) {
    const float4 kwe = kw[bN + e];
    const float4 v = *reinterpret_cast<const float4*>(&fts_s[(bN + e) * D + d4]);
    const bool neg = (kwe.x <= th);
    const float wn = neg ? kwe.z : 0.f;
    const float wp = neg ? 0.f : kwe.y;
    sn.x += wn * v.x; sn.y += wn * v.y; sn.z += wn * v.z; sn.w += wn * v.w;
    sp.x += wp * v.x; sp.y += wp * v.y; sp.z += wp * v.z; sp.w += wp * v.w;
    cn += wn; cp += wp;
  }
  const float wqp = expf(f1v), wqn = expf(ALPHA * f1v);
  const float denom = wqp * cp + wqn * cn;
  const float inv = 1.0f / denom;
  const float4 bi = *reinterpret_cast<const float4*>(&bias[d4]);
  float4 val;
  val.x = (wqp * sp.x + wqn * sn.x) * inv + bi.x;
  val.y = (wqp * sp.y + wqn * sn.y) * inv + bi.y;
  val.z = (wqp * sp.z + wqn * sn.z) * inv + bi.z;
  val.w = (wqp * sp.w + wqn * sn.w) * inv + bi.w;
  val.x = val.x >= 0.f ? val.x : ALPHA * val.x;
  val.y = val.y >= 0.f ? val.y : ALPHA * val.y;
  val.z = val.z >= 0.f ? val.z : ALPHA * val.z;
  val.w = val.w >= 0.f ? val.w : ALPHA * val.w;
  *reinterpret_cast<float4*>(&out[(size_t)row * D + d4]) = val;
}

extern "C" void kernel_launch(void* const* d_in, const int* in_sizes, int n_in,
                              void* d_out, int out_size, void* d_ws, size_t ws_size,
                              hipStream_t stream) {
  const float* seq  = (const float*)d_in[0];
  const float* Wf   = (const float*)d_in[1];
  const float* w1   = (const float*)d_in[2];
  const float* b1   = (const float*)d_in[3];
  const float* w2   = (const float*)d_in[4];
  const float* b2   = (const float*)d_in[5];
  const float* bias = (const float*)d_in[6];
  float* out = (float*)d_out;

  char* ws = (char*)d_ws;
  size_t off = 0;
  auto alloc = [&](size_t bytes) -> void* {
    void* p = ws + off;
    off = (off + bytes + 255) & ~(size_t)255;
    return p;
  };

  float*  fts     = (float*) alloc((size_t)M * D * 4);
  float*  fts_s   = (float*) alloc((size_t)M * D * 4);
  float*  f1      = (float*) alloc((size_t)M * 4);
  float*  f2      = (float*) alloc((size_t)M * 4);
  float4* kw      = (float4*)alloc((size_t)M * 16);
  int*    idxs    = (int*)   alloc((size_t)M * 4);
  int*    bid     = (int*)   alloc((size_t)M * 4);
  int*    histcnt = (int*)   alloc((size_t)B * P * NB * 4);
  int*    substart= (int*)   alloc((size_t)B * P * NB * 4);
  int*    btot    = (int*)   alloc((size_t)B * NB * 4);
  int*    bstart  = (int*)   alloc((size_t)B * (NB + 1) * 4);
  float*  Wp      = (float*) alloc((size_t)B * NB * D * 4);
  float*  Wn      = (float*) alloc((size_t)B * NB * D * 4);
  float*  Cp      = (float*) alloc((size_t)B * NB * 4);
  float*  Cn      = (float*) alloc((size_t)B * NB * 4);
  float*  BPos    = (float*) alloc((size_t)B * NB * D * 4);
  float*  BNeg    = (float*) alloc((size_t)B * NB * D * 4);
  float*  CpB     = (float*) alloc((size_t)B * NB * 4);
  float*  CnB     = (float*) alloc((size_t)B * NB * 4);

  hipLaunchKernelGGL(k_gemm,  dim3(M / 64),          dim3(512), 0, stream, seq, Wf, w1, b1, w2, b2, fts, f1, f2);
  hipLaunchKernelGGL(k_hist,  dim3(B * P),           dim3(128), 0, stream, f2, bid, histcnt);
  hipLaunchKernelGGL(k_sub,   dim3(B * NB / 256),    dim3(256), 0, stream, histcnt, substart, btot);
  hipLaunchKernelGGL(k_scat,  dim3(B * P),           dim3(128), 0, stream, f2, bid, substart, btot, bstart,
                     kw, idxs);
  hipLaunchKernelGGL(k_perm,  dim3(M * D / 4 / 256), dim3(256), 0, stream, fts, idxs, fts_s);
  hipLaunchKernelGGL(k_bsum,  dim3(B * NBB),         dim3(128), 0, stream, fts_s, kw, bstart, Wp, Wn, Cp, Cn);
  hipLaunchKernelGGL(k_scan,  dim3(B * NSL),         dim3(128), 0, stream, Wp, Wn, Cp, Cn, BPos, BNeg, CpB, CnB);
  hipLaunchKernelGGL(k_query, dim3(M / QROWS),       dim3(256), 0, stream, f1, kw, fts_s, bstart,
                     BPos, BNeg, CpB, CnB, bias, out);
}

// Round 17
// 85.892 us; speedup vs baseline: 1.2096x; 1.0029x over previous
//
#include <hip/hip_runtime.h>
#include <cstddef>

#define ALPHA 0.2f
constexpr int B = 2, N = 8192, F = 256, D = 128;
constexpr int M = B * N;
constexpr int NB = 2048;          // value buckets per batch
constexpr int SUB = 128;          // elements per sub-block for stable scatter
constexpr int P = N / SUB;        // 64 sub-blocks per batch
constexpr int GB = 2;             // buckets per k_bsum block
constexpr int NBB = NB / GB;      // 1024 bsum blocks per batch
constexpr int GSZ = 32;           // buckets per scan group
constexpr int NGRP = NB / GSZ;    // 64 groups per batch
constexpr int QROWS = 8;          // rows per k_query block
constexpr int DSL = 2;            // d's per k_scan slice
constexpr int NSL = D / DSL;      // 64 slices
constexpr int BPT = NB / 128;     // buckets per thread in k_scat local scan (16)

// ---- fixed monotone bucket map over [-4.5,4.5) (clamped ends stay exactly correct) ----
#define BMIN (-4.5f)
#define BSCALE ((float)NB / 9.0f)
__device__ inline int bucket_of(float x) {
  int g = (int)((x - BMIN) * BSCALE);
  return g < 0 ? 0 : (g > NB - 1 ? NB - 1 : g);
}

// ---------------- GEMM (fp32, per-thread 4x4, 32-row tile, 2 blocks/CU) + fused f1/f2 ----------------
// 256 threads; thread = (rowg 0..7, colg 0..31); rows rowg*4..+3, cols colg*4..+3.
// Same k-ascending accumulation as R14/R16 -> fts bitwise identical.
__global__ __launch_bounds__(256) void k_gemm(const float* __restrict__ seq,
                                              const float* __restrict__ Wf,
                                              const float* __restrict__ w1,
                                              const float* __restrict__ b1,
                                              const float* __restrict__ w2,
                                              const float* __restrict__ b2,
                                              float* __restrict__ fts,
                                              float* __restrict__ f1,
                                              float* __restrict__ f2) {
  __shared__ float As[32][36];    // [k][row], 144B row stride (16B-aligned)
  __shared__ float Bs[32][128];
  const int m0 = blockIdx.x * 32;
  const int t = threadIdx.x;
  const int colg = t & 31;        // cols colg*4 .. +3
  const int rowg = t >> 5;        // rows rowg*4 .. +3 (8 groups)
  float acc[4][4];
#pragma unroll
  for (int r = 0; r < 4; ++r)
#pragma unroll
    for (int c = 0; c < 4; ++c) acc[r][c] = 0.f;

  for (int kc = 0; kc < F; kc += 32) {
    {  // stage A 32x32 transposed [k][row]: one float4 per thread
      const int row = t >> 3, k4 = t & 7;
      const float4 v = *reinterpret_cast<const float4*>(
          &seq[(size_t)(m0 + row) * F + kc + k4 * 4]);
      As[k4 * 4 + 0][row] = v.x; As[k4 * 4 + 1][row] = v.y;
      As[k4 * 4 + 2][row] = v.z; As[k4 * 4 + 3][row] = v.w;
    }
#pragma unroll
    for (int it = 0; it < 4; ++it) {  // stage B 32x128: four float4 per thread
      const int fid = t + it * 256;
      const int row = fid >> 5, c4 = fid & 31;
      *reinterpret_cast<float4*>(&Bs[row][c4 * 4]) =
          *reinterpret_cast<const float4*>(&Wf[(size_t)(kc + row) * D + c4 * 4]);
    }
    __syncthreads();
#pragma unroll
    for (int k = 0; k < 32; ++k) {
      const float4 a4 = *reinterpret_cast<const float4*>(&As[k][rowg * 4]);
      const float4 b4 = *reinterpret_cast<const float4*>(&Bs[k][colg * 4]);
      acc[0][0] += a4.x * b4.x; acc[0][1] += a4.x * b4.y; acc[0][2] += a4.x * b4.z; acc[0][3] += a4.x * b4.w;
      acc[1][0] += a4.y * b4.x; acc[1][1] += a4.y * b4.y; acc[1][2] += a4.y * b4.z; acc[1][3] += a4.y * b4.w;
      acc[2][0] += a4.z * b4.x; acc[2][1] += a4.z * b4.y; acc[2][2] += a4.z * b4.z; acc[2][3] += a4.z * b4.w;
      acc[3][0] += a4.w * b4.x; acc[3][1] += a4.w * b4.y; acc[3][2] += a4.w * b4.z; acc[3][3] += a4.w * b4.w;
    }
    __syncthreads();
  }
#pragma unroll
  for (int r = 0; r < 4; ++r) {
    float4 v = {acc[r][0], acc[r][1], acc[r][2], acc[r][3]};
    *reinterpret_cast<float4*>(&fts[(size_t)(m0 + rowg * 4 + r) * D + colg * 4]) = v;
  }
  // fused f1/f2: thread's 4 cols partial dot, width-32 shuffle reduce covers the full row
  const float w1v[4] = {w1[colg * 4], w1[colg * 4 + 1], w1[colg * 4 + 2], w1[colg * 4 + 3]};
  const float w2v[4] = {w2[colg * 4], w2[colg * 4 + 1], w2[colg * 4 + 2], w2[colg * 4 + 3]};
  const float b1v = b1[0], b2v = b2[0];
#pragma unroll
  for (int r = 0; r < 4; ++r) {
    float s1 = acc[r][0] * w1v[0] + acc[r][1] * w1v[1] + acc[r][2] * w1v[2] + acc[r][3] * w1v[3];
    float s2 = acc[r][0] * w2v[0] + acc[r][1] * w2v[1] + acc[r][2] * w2v[2] + acc[r][3] * w2v[3];
#pragma unroll
    for (int off = 16; off > 0; off >>= 1) {
      s1 += __shfl_down(s1, off, 32);
      s2 += __shfl_down(s2, off, 32);
    }
    if (colg == 0) {
      const int row = m0 + rowg * 4 + r;
      f1[row] = s1 + b1v;
      f2[row] = s2 + b2v;
    }
  }
}

// ---------------- per-sub-block histogram (deterministic) ----------------
__global__ __launch_bounds__(128) void k_hist(const float* __restrict__ f2,
                                              int* __restrict__ bid,
                                              int* __restrict__ histcnt) {
  __shared__ int hist[NB];
  const int b = blockIdx.x / P, p = blockIdx.x % P;
  const int t = threadIdx.x;
  for (int i = t; i < NB; i += 128) hist[i] = 0;
  const int j = p * SUB + t;
  float x = f2[b * N + j];
  int g = bucket_of(x);
  bid[b * N + j] = g;
  __syncthreads();
  atomicAdd(&hist[g], 1);
  __syncthreads();
  for (int i = t; i < NB; i += 128)
    histcnt[((size_t)(b * P + p)) * NB + i] = hist[i];
}

// ---------------- per-bucket prefix over sub-blocks + bucket totals ----------------
__global__ __launch_bounds__(256) void k_sub(const int* __restrict__ histcnt,
                                             int* __restrict__ substart,
                                             int* __restrict__ btot) {
  const int gid = blockIdx.x * 256 + threadIdx.x;  // 0 .. B*NB-1
  const int b = gid / NB, g = gid % NB;
  int run = 0;
  for (int pp = 0; pp < P; ++pp) {
    substart[((size_t)(b * P + pp)) * NB + g] = run;
    run += histcnt[((size_t)(b * P + pp)) * NB + g];
  }
  btot[b * NB + g] = run;
}

// ---------------- scatter of keys/weights (packed kw), local bucket scan ----------------
__global__ __launch_bounds__(128) void k_scat(const float* __restrict__ f2,
                                              const int* __restrict__ bid,
                                              const int* __restrict__ substart,
                                              const int* __restrict__ btot,
                                              int* __restrict__ bstart,
                                              float4* __restrict__ kw,
                                              int* __restrict__ idxs) {
  __shared__ int bstart_lds[NB];
  __shared__ int bids[SUB];
  __shared__ int wsum2[2];
  const int b = blockIdx.x / P, p = blockIdx.x % P;
  const int t = threadIdx.x;
  const int lane = t & 63, wave = t >> 6;
  const size_t bN = (size_t)b * N;

  int c[BPT];
  int loc = 0;
#pragma unroll
  for (int i = 0; i < BPT; ++i) { c[i] = btot[b * NB + t * BPT + i]; loc += c[i]; }
  int incl = loc;
#pragma unroll
  for (int off = 1; off < 64; off <<= 1) {
    int y = __shfl_up(incl, off);
    if (lane >= off) incl += y;
  }
  if (lane == 63) wsum2[wave] = incl;
  __syncthreads();
  if (wave == 1) incl += wsum2[0];
  int excl = incl - loc;
#pragma unroll
  for (int i = 0; i < BPT; ++i) { bstart_lds[t * BPT + i] = excl; excl += c[i]; }
  __syncthreads();
  if (p == 0) {
    for (int i = t; i < NB; i += 128) bstart[b * (NB + 1) + i] = bstart_lds[i];
    if (t == 0) bstart[b * (NB + 1) + NB] = N;
  }

  const int j = p * SUB + t;
  const int g = bid[bN + j];
  bids[t] = g;
  __syncthreads();
  int off = bstart_lds[g] + substart[((size_t)(b * P + p)) * NB + g];
  for (int jj = 0; jj < t; ++jj) off += (bids[jj] == g);
  const float x = f2[bN + j];
  kw[bN + off] = make_float4(x, expf(x), expf(ALPHA * x), 0.f);
  idxs[bN + off] = j;
}

// ---------------- permute fts into scattered order (full-grid gather) ----------------
__global__ __launch_bounds__(256) void k_perm(const float* __restrict__ fts,
                                              const int* __restrict__ idxs,
                                              float* __restrict__ fts_s) {
  const int tid = blockIdx.x * 256 + threadIdx.x;    // one float4 each
  const int eg = tid >> 5;                           // global scattered row (b*N+e)
  const int q = tid & 31;
  const int b = eg / N;
  const int j = idxs[eg];
  *reinterpret_cast<float4*>(&fts_s[(size_t)eg * D + q * 4]) =
      *reinterpret_cast<const float4*>(&fts[((size_t)b * N + j) * D + q * 4]);
}

// ---------------- per-bucket weighted sums (streaming, high TLP) ----------------
__global__ __launch_bounds__(128) void k_bsum(const float* __restrict__ fts_s,
                                              const float4* __restrict__ kw,
                                              const int* __restrict__ bstart,
                                              float* __restrict__ Wp, float* __restrict__ Wn,
                                              float* __restrict__ Cp, float* __restrict__ Cn) {
  const int b = blockIdx.x / NBB, blk = blockIdx.x % NBB;
  const int d = threadIdx.x;
  const int gbase = blk * GB;
  const size_t bN = (size_t)b * N;
  for (int gg = 0; gg < GB; ++gg) {
    const int g = gbase + gg;
    const int e0 = bstart[b * (NB + 1) + g], e1 = bstart[b * (NB + 1) + g + 1];
    float ap = 0.f, an = 0.f, sp = 0.f, sn = 0.f;
    int e = e0;
    for (; e + 4 <= e1; e += 4) {
      const float* vp = &fts_s[(bN + e) * D + d];
      const float v0 = vp[0], v1 = vp[D], v2 = vp[2 * D], v3 = vp[3 * D];
      const float4 k0 = kw[bN + e], k1 = kw[bN + e + 1], k2 = kw[bN + e + 2], k3 = kw[bN + e + 3];
      ap += k0.y * v0 + k1.y * v1 + k2.y * v2 + k3.y * v3;
      an += k0.z * v0 + k1.z * v1 + k2.z * v2 + k3.z * v3;
      sp += k0.y + k1.y + k2.y + k3.y;
      sn += k0.z + k1.z + k2.z + k3.z;
    }
    for (; e < e1; ++e) {
      const float v = fts_s[(bN + e) * D + d];
      const float4 k0 = kw[bN + e];
      ap += k0.y * v; an += k0.z * v; sp += k0.y; sn += k0.z;
    }
    Wp[((size_t)b * NB + g) * D + d] = ap;
    Wn[((size_t)b * NB + g) * D + d] = an;
    if (d == 0) { Cp[b * NB + g] = sp; Cn[b * NB + g] = sn; }
  }
}

// ---------------- fused 3-phase bucket-boundary scan (GSZ=32, 128 blocks) ----------------
__global__ __launch_bounds__(128) void k_scan(const float* __restrict__ Wp, const float* __restrict__ Wn,
                                              const float* __restrict__ Cp, const float* __restrict__ Cn,
                                              float* __restrict__ BPos, float* __restrict__ BNeg,
                                              float* __restrict__ CpB, float* __restrict__ CnB) {
  __shared__ float gp[NGRP][DSL], gn[NGRP][DSL];
  __shared__ float cgp[NGRP], cgn[NGRP];
  const int b = blockIdx.x / NSL, sl = blockIdx.x % NSL;
  const int t = threadIdx.x;                 // 128 = NGRP(64) x DSL(2)
  const int d4 = t & (DSL - 1), grp = t >> 1;
  const int d = sl * DSL + d4;
  const size_t base = (size_t)b * NB;

  float sp = 0.f, sn = 0.f;
  for (int gg = 0; gg < GSZ; ++gg) {
    const int g = grp * GSZ + gg;
    sp += Wp[(base + g) * D + d];
    sn += Wn[(base + g) * D + d];
  }
  gp[grp][d4] = sp; gn[grp][d4] = sn;
  if (sl == 0 && d4 == 0) {
    float cp = 0.f, cn = 0.f;
    for (int gg = 0; gg < GSZ; ++gg) { const int g = grp * GSZ + gg; cp += Cp[base + g]; cn += Cn[base + g]; }
    cgp[grp] = cp; cgn[grp] = cn;
  }
  __syncthreads();

  if (t < DSL) {
    float run = 0.f;
    for (int g2 = 0; g2 < NGRP; ++g2) { const float v = gn[g2][t]; gn[g2][t] = run; run += v; }
  } else if (t < 2 * DSL) {
    const int dd = t - DSL;
    float run = 0.f;
    for (int g2 = NGRP - 1; g2 >= 0; --g2) { const float v = gp[g2][dd]; gp[g2][dd] = run; run += v; }
  } else if (sl == 0 && t == 2 * DSL) {
    float run = 0.f;
    for (int g2 = 0; g2 < NGRP; ++g2) { const float v = cgn[g2]; cgn[g2] = run; run += v; }
  } else if (sl == 0 && t == 2 * DSL + 1) {
    float run = 0.f;
    for (int g2 = NGRP - 1; g2 >= 0; --g2) { const float v = cgp[g2]; cgp[g2] = run; run += v; }
  }
  __syncthreads();

  float runn = gn[grp][d4];
  for (int gg = 0; gg < GSZ; ++gg) {
    const int g = grp * GSZ + gg;
    BNeg[(base + g) * D + d] = runn;
    runn += Wn[(base + g) * D + d];
  }
  float runp = gp[grp][d4];
  for (int gg = GSZ - 1; gg >= 0; --gg) {
    const int g = grp * GSZ + gg;
    BPos[(base + g) * D + d] = runp;
    runp += Wp[(base + g) * D + d];
  }
  if (sl == 0 && d4 == 0) {
    float rn = cgn[grp];
    for (int gg = 0; gg < GSZ; ++gg) { const int g = grp * GSZ + gg; CnB[base + g] = rn; rn += Cn[base + g]; }
    float rp = cgp[grp];
    for (int gg = GSZ - 1; gg >= 0; --gg) { const int g = grp * GSZ + gg; CpB[base + g] = rp; rp += Cp[base + g]; }
  }
}

// ---------------- query: 32 lanes x float4 per row, branchless boundary loop ----------------
__global__ __launch_bounds__(256) void k_query(const float* __restrict__ f1,
                                               const float4* __restrict__ kw,
                                               const float* __restrict__ fts_s,
                                               const int* __restrict__ bstart,
                                               const float* __restrict__ BPos, const float* __restrict__ BNeg,
                                               const float* __restrict__ CpB, const float* __restrict__ CnB,
                                               const float* __restrict__ bias,
                                               float* __restrict__ out) {
  const int r = threadIdx.x >> 5;
  const int lane = threadIdx.x & 31;
  const int row = blockIdx.x * QROWS + r;
  const int b = row / N;
  const size_t bN = (size_t)b * N;
  const int d4 = lane * 4;
  const float f1v = f1[row];
  const float th = -f1v;
  const int g = bucket_of(th);
  const int base = bstart[b * (NB + 1) + g];
  const int end  = bstart[b * (NB + 1) + g + 1];
  float4 sn = *reinterpret_cast<const float4*>(&BNeg[((size_t)b * NB + g) * D + d4]);
  float4 sp = *reinterpret_cast<const float4*>(&BPos[((size_t)b * NB + g) * D + d4]);
  float cn = CnB[b * NB + g];
  float cp = CpB[b * NB + g];
  for (int e = base; e < end; ++e) {
    const float4 kwe = kw[bN + e];
    const float4 v = *reinterpret_cast<const float4*>(&fts_s[(bN + e) * D + d4]);
    const bool neg = (kwe.x <= th);
    const float wn = neg ? kwe.z : 0.f;
    const float wp = neg ? 0.f : kwe.y;
    sn.x += wn * v.x; sn.y += wn * v.y; sn.z += wn * v.z; sn.w += wn * v.w;
    sp.x += wp * v.x; sp.y += wp * v.y; sp.z += wp * v.z; sp.w += wp * v.w;
    cn += wn; cp += wp;
  }
  const float wqp = expf(f1v), wqn = expf(ALPHA * f1v);
  const float denom = wqp * cp + wqn * cn;
  const float inv = 1.0f / denom;
  const float4 bi = *reinterpret_cast<const float4*>(&bias[d4]);
  float4 val;
  val.x = (wqp * sp.x + wqn * sn.x) * inv + bi.x;
  val.y = (wqp * sp.y + wqn * sn.y) * inv + bi.y;
  val.z = (wqp * sp.z + wqn * sn.z) * inv + bi.z;
  val.w = (wqp * sp.w + wqn * sn.w) * inv + bi.w;
  val.x = val.x >= 0.f ? val.x : ALPHA * val.x;
  val.y = val.y >= 0.f ? val.y : ALPHA * val.y;
  val.z = val.z >= 0.f ? val.z : ALPHA * val.z;
  val.w = val.w >= 0.f ? val.w : ALPHA * val.w;
  *reinterpret_cast<float4*>(&out[(size_t)row * D + d4]) = val;
}

extern "C" void kernel_launch(void* const* d_in, const int* in_sizes, int n_in,
                              void* d_out, int out_size, void* d_ws, size_t ws_size,
                              hipStream_t stream) {
  const float* seq  = (const float*)d_in[0];
  const float* Wf   = (const float*)d_in[1];
  const float* w1   = (const float*)d_in[2];
  const float* b1   = (const float*)d_in[3];
  const float* w2   = (const float*)d_in[4];
  const float* b2   = (const float*)d_in[5];
  const float* bias = (const float*)d_in[6];
  float* out = (float*)d_out;

  char* ws = (char*)d_ws;
  size_t off = 0;
  auto alloc = [&](size_t bytes) -> void* {
    void* p = ws + off;
    off = (off + bytes + 255) & ~(size_t)255;
    return p;
  };

  float*  fts     = (float*) alloc((size_t)M * D * 4);
  float*  fts_s   = (float*) alloc((size_t)M * D * 4);
  float*  f1      = (float*) alloc((size_t)M * 4);
  float*  f2      = (float*) alloc((size_t)M * 4);
  float4* kw      = (float4*)alloc((size_t)M * 16);
  int*    idxs    = (int*)   alloc((size_t)M * 4);
  int*    bid     = (int*)   alloc((size_t)M * 4);
  int*    histcnt = (int*)   alloc((size_t)B * P * NB * 4);
  int*    substart= (int*)   alloc((size_t)B * P * NB * 4);
  int*    btot    = (int*)   alloc((size_t)B * NB * 4);
  int*    bstart  = (int*)   alloc((size_t)B * (NB + 1) * 4);
  float*  Wp      = (float*) alloc((size_t)B * NB * D * 4);
  float*  Wn      = (float*) alloc((size_t)B * NB * D * 4);
  float*  Cp      = (float*) alloc((size_t)B * NB * 4);
  float*  Cn      = (float*) alloc((size_t)B * NB * 4);
  float*  BPos    = (float*) alloc((size_t)B * NB * D * 4);
  float*  BNeg    = (float*) alloc((size_t)B * NB * D * 4);
  float*  CpB     = (float*) alloc((size_t)B * NB * 4);
  float*  CnB     = (float*) alloc((size_t)B * NB * 4);

  hipLaunchKernelGGL(k_gemm,  dim3(M / 32),          dim3(256), 0, stream, seq, Wf, w1, b1, w2, b2, fts, f1, f2);
  hipLaunchKernelGGL(k_hist,  dim3(B * P),           dim3(128), 0, stream, f2, bid, histcnt);
  hipLaunchKernelGGL(k_sub,   dim3(B * NB / 256),    dim3(256), 0, stream, histcnt, substart, btot);
  hipLaunchKernelGGL(k_scat,  dim3(B * P),           dim3(128), 0, stream, f2, bid, substart, btot, bstart,
                     kw, idxs);
  hipLaunchKernelGGL(k_perm,  dim3(M * D / 4 / 256), dim3(256), 0, stream, fts, idxs, fts_s);
  hipLaunchKernelGGL(k_bsum,  dim3(B * NBB),         dim3(128), 0, stream, fts_s, kw, bstart, Wp, Wn, Cp, Cn);
  hipLaunchKernelGGL(k_scan,  dim3(B * NSL),         dim3(128), 0, stream, Wp, Wn, Cp, Cn, BPos, BNeg, CpB, CnB);
  hipLaunchKernelGGL(k_query, dim3(M / QROWS),       dim3(256), 0, stream, f1, kw, fts_s, bstart,
                     BPos, BNeg, CpB, CnB, bias, out);
}